// Round 1
// baseline (490.239 us; speedup 1.0000x reference)
//
#include <hip/hip_runtime.h>

typedef short short8 __attribute__((ext_vector_type(8)));
typedef float f32x4 __attribute__((ext_vector_type(4)));

__device__ __forceinline__ unsigned short f2bf(float f) {
    unsigned u = __float_as_uint(f);
    u += 0x7fffu + ((u >> 16) & 1u);
    return (unsigned short)(u >> 16);
}
__device__ __forceinline__ float bf2f(unsigned short h) {
    return __uint_as_float(((unsigned)h) << 16);
}

// ---------------- ws init (2 absmax words) ----------------
__global__ void init_ws_kernel(unsigned* p) {
    if (threadIdx.x < 2) p[threadIdx.x] = 0u;
}

// ---------------- absmax reduction (float4 grid-stride + wave shuffle + atomicMax on bits) ----
__global__ void absmax_kernel(const float* __restrict__ w, int n4, unsigned* __restrict__ out) {
    float m = 0.0f;
    const int stride = gridDim.x * blockDim.x;
    for (int i = blockIdx.x * blockDim.x + threadIdx.x; i < n4; i += stride) {
        float4 v = ((const float4*)w)[i];
        m = fmaxf(m, fmaxf(fmaxf(fabsf(v.x), fabsf(v.y)), fmaxf(fabsf(v.z), fabsf(v.w))));
    }
#pragma unroll
    for (int off = 32; off > 0; off >>= 1)
        m = fmaxf(m, __shfl_down(m, off));
    if ((threadIdx.x & 63) == 0)
        atomicMax(out, __float_as_uint(m));
}

// ---------------- weight fake-quant -> integer codes in bf16, layout Wt[n][(kh*3+kw)*CIN+cin] ---
template<int CIN>
__global__ void quant_w_kernel(const float* __restrict__ w, const unsigned* __restrict__ absbits,
                               unsigned short* __restrict__ wt, int total) {
    const int idx = blockIdx.x * blockDim.x + threadIdx.x;
    if (idx >= total) return;
    constexpr int K = 9 * CIN;
    const int n = idx / K;
    const int k = idx - n * K;
    const int r = k / CIN;
    const int cin = k - r * CIN;
    const int kh = r / 3;
    const int kw = r - kh * 3;
    const float s = __uint_as_float(*absbits) * (1.0f / 127.0f);
    const float v = w[(((long)n * CIN + cin) * 3 + kh) * 3 + kw];
    float q = rintf(v / s);
    q = fminf(fmaxf(q, -127.0f), 127.0f);   // narrow int8 range
    wt[idx] = f2bf(q);
}

// ---------------- bias Int32 fake-quant (scale = s_prev * s_w) ----------------
__global__ void quant_bias_kernel(const float* __restrict__ b1, const float* __restrict__ b2,
                                  const unsigned* __restrict__ a1, const unsigned* __restrict__ a2,
                                  const float* __restrict__ in_scale, const float* __restrict__ act1_scale,
                                  float* __restrict__ bq1, float* __restrict__ bq2) {
    const int i = blockIdx.x * blockDim.x + threadIdx.x;
    if (i < 512) {
        const float s = (*in_scale) * (__uint_as_float(*a1) * (1.0f / 127.0f));
        float q = rintf(b1[i] / s);
        q = fminf(fmaxf(q, -2147483648.0f), 2147483648.0f);
        bq1[i] = q * s;
    } else if (i < 1024) {
        const int j = i - 512;
        const float s = (*act1_scale) * (__uint_as_float(*a2) * (1.0f / 127.0f));
        float q = rintf(b2[j] / s);
        q = fminf(fmaxf(q, -2147483648.0f), 2147483648.0f);
        bq2[j] = q * s;
    }
}

// ---------------- x: fp32 NCHW -> bf16 hi/lo NHWC (tiled transpose) ----------------
// per b: [256][784] -> [784][256]
__global__ __launch_bounds__(256) void xform_x_kernel(const float* __restrict__ x,
                                                      unsigned short* __restrict__ hi,
                                                      unsigned short* __restrict__ lo) {
    __shared__ float t[32][33];
    const int tx = threadIdx.x & 31;
    const int ty = threadIdx.x >> 5;     // 0..7
    const int b = blockIdx.z;
    const int c0 = blockIdx.y * 32;
    const int hw0 = blockIdx.x * 32;
#pragma unroll
    for (int i = 0; i < 4; ++i) {
        const int c = c0 + ty + i * 8;
        const int hw = hw0 + tx;
        float v = 0.0f;
        if (hw < 784) v = x[((long)b * 256 + c) * 784 + hw];
        t[ty + i * 8][tx] = v;
    }
    __syncthreads();
#pragma unroll
    for (int i = 0; i < 4; ++i) {
        const int hw = hw0 + ty + i * 8;
        const int c = c0 + tx;
        if (hw < 784) {
            const float v = t[tx][ty + i * 8];
            const unsigned short h = f2bf(v);
            const unsigned short l = f2bf(v - bf2f(h));
            const long o = ((long)b * 784 + hw) * 256 + c;
            hi[o] = h;
            lo[o] = l;
        }
    }
}

// ---------------- implicit-GEMM conv with MFMA bf16 ----------------
// A: NHWC bf16 (integer codes or hi/lo split), Wt: [512][9*CIN] integer codes in bf16.
// Tile: 64(m) x 64(n) per block, 4 waves, each wave 16m x 64n via 4x mfma_f32_16x16x32_bf16.
// k-order: k = (kh*3+kw)*CIN + cin  (BK=32 stays within one (kh,kw) since 32 | CIN).
template<int CIN, int STRIDE, int HIN, int HOUT, bool SPLIT, bool FINAL>
__global__ __launch_bounds__(256) void conv_gemm_kernel(
    const unsigned short* __restrict__ Ahi,
    const unsigned short* __restrict__ Alo,
    const unsigned short* __restrict__ Wt,
    const float* __restrict__ bias,
    const unsigned* __restrict__ wabs,
    const float* __restrict__ s_pre,   // act1 scale (used only when FINAL)
    const float* __restrict__ s_act,   // epilogue act scale
    unsigned short* __restrict__ act_out,  // !FINAL: NHWC bf16 integer codes
    float* __restrict__ out_final)         // FINAL: NCHW fp32
{
    constexpr int K = 9 * CIN;
    constexpr int HW = HOUT * HOUT;
    __shared__ __align__(16) unsigned short As[64 * 40];
    __shared__ __align__(16) unsigned short As2[64 * 40];
    __shared__ __align__(16) unsigned short Bs[64 * 40];

    const int tid = threadIdx.x;
    const int m0 = blockIdx.y * 64;
    const int n0 = blockIdx.x * 64;

    // staging assignment: thread -> (row, 8-elem k-chunk)
    const int mload = tid >> 2;          // 0..63
    const int kk = (tid & 3) * 8;        // 0,8,16,24
    const int m = m0 + mload;
    const int b = m / HW;
    const int rem = m - b * HW;
    const int oh = rem / HOUT;
    const int ow = rem - oh * HOUT;
    const long nrow = (long)(n0 + mload) * K;

    const int lane = tid & 63;
    const int wv = tid >> 6;             // wave 0..3 -> m rows [wv*16, wv*16+16)
    const int quad = lane >> 4;
    const int l16 = lane & 15;

    f32x4 acc[4] = {f32x4{0,0,0,0}, f32x4{0,0,0,0}, f32x4{0,0,0,0}, f32x4{0,0,0,0}};

    for (int k0 = 0; k0 < K; k0 += 32) {
        const int r = k0 / CIN;
        const int kh = r / 3;
        const int kw = r - kh * 3;
        const int cin = k0 - r * CIN + kk;
        const int ih = oh * STRIDE - 1 + kh;
        const int iw = ow * STRIDE - 1 + kw;
        uint4 va = {0, 0, 0, 0}, va2 = {0, 0, 0, 0};
        if ((unsigned)ih < (unsigned)HIN && (unsigned)iw < (unsigned)HIN) {
            const long idx = ((long)((b * HIN + ih) * HIN + iw)) * CIN + cin;
            va = *(const uint4*)(Ahi + idx);
            if (SPLIT) va2 = *(const uint4*)(Alo + idx);
        }
        const uint4 vb = *(const uint4*)(Wt + nrow + k0 + kk);

        __syncthreads();   // previous iter's frag reads done
        *(uint4*)&As[mload * 40 + kk] = va;
        if (SPLIT) *(uint4*)&As2[mload * 40 + kk] = va2;
        *(uint4*)&Bs[mload * 40 + kk] = vb;
        __syncthreads();

        // A frag: A[m = l16][k = quad*8+j];  B frag: B[k = quad*8+j][n = l16] (from Bt[n][k])
        const short8 a0 = *(const short8*)&As[(wv * 16 + l16) * 40 + quad * 8];
        short8 a1;
        if (SPLIT) a1 = *(const short8*)&As2[(wv * 16 + l16) * 40 + quad * 8];
#pragma unroll
        for (int ns = 0; ns < 4; ++ns) {
            const short8 bfrag = *(const short8*)&Bs[(ns * 16 + l16) * 40 + quad * 8];
            acc[ns] = __builtin_amdgcn_mfma_f32_16x16x32_bf16(a0, bfrag, acc[ns], 0, 0, 0);
            if (SPLIT) acc[ns] = __builtin_amdgcn_mfma_f32_16x16x32_bf16(a1, bfrag, acc[ns], 0, 0, 0);
        }
    }

    // epilogue: dequant weights (+ prev act scale), add quantized bias, act fake-quant
    float alpha = __uint_as_float(*wabs) * (1.0f / 127.0f);
    if (FINAL) alpha *= *s_pre;
    const float sact = *s_act;

#pragma unroll
    for (int ns = 0; ns < 4; ++ns) {
        const int n = n0 + ns * 16 + l16;
        const float bv = bias[n];
#pragma unroll
        for (int i = 0; i < 4; ++i) {
            const int mm = m0 + wv * 16 + quad * 4 + i;   // D[row=quad*4+i][col=l16]
            const float v = acc[ns][i] * alpha + bv;
            float q = rintf(v / sact);
            q = fminf(fmaxf(q, -128.0f), 127.0f);         // full int8 range
            const int bb = mm / HW;
            const int rr = mm - bb * HW;
            const int o_h = rr / HOUT;
            const int o_w = rr - o_h * HOUT;
            if (FINAL) {
                out_final[(((long)bb * 512 + n) * HOUT + o_h) * HOUT + o_w] = q * sact;
            } else {
                act_out[(((long)bb * HOUT + o_h) * HOUT + o_w) * 512 + n] = f2bf(q);
            }
        }
    }
}

// ---------------- launch ----------------
extern "C" void kernel_launch(void* const* d_in, const int* in_sizes, int n_in,
                              void* d_out, int out_size, void* d_ws, size_t ws_size,
                              hipStream_t stream) {
    const float* x  = (const float*)d_in[0];   // 64x256x28x28
    const float* w1 = (const float*)d_in[1];   // 512x256x3x3
    const float* b1 = (const float*)d_in[2];   // 512
    const float* w2 = (const float*)d_in[3];   // 512x512x3x3
    const float* b2 = (const float*)d_in[4];   // 512
    const float* in_scale   = (const float*)d_in[5];
    const float* act1_scale = (const float*)d_in[6];
    const float* act2_scale = (const float*)d_in[7];
    float* out = (float*)d_out;                // 64x512x14x14 NCHW fp32

    char* ws = (char*)d_ws;
    // ws layout (bytes)
    unsigned* abs1 = (unsigned*)(ws + 0);
    unsigned* abs2 = (unsigned*)(ws + 4);
    float* bq1 = (float*)(ws + 64);                       // 512 f
    float* bq2 = (float*)(ws + 2112);                     // 512 f
    unsigned short* wq1 = (unsigned short*)(ws + 8192);   // 512*2304 = 2359296 B
    unsigned short* wq2 = (unsigned short*)(ws + 2367488);// 512*4608 = 4718592 B
    unsigned short* xhi = (unsigned short*)(ws + 7086080);   // 12845056*2
    unsigned short* xlo = (unsigned short*)(ws + 32776192);  // 12845056*2
    unsigned short* act = (unsigned short*)(ws + 58466304);  // 6422528*2 -> ends 71311360

    init_ws_kernel<<<1, 64, 0, stream>>>((unsigned*)ws);

    absmax_kernel<<<256, 256, 0, stream>>>(w1, 512 * 256 * 9 / 4, abs1);
    absmax_kernel<<<256, 256, 0, stream>>>(w2, 512 * 512 * 9 / 4, abs2);

    quant_w_kernel<256><<<(512 * 2304) / 256, 256, 0, stream>>>(w1, abs1, wq1, 512 * 2304);
    quant_w_kernel<512><<<(512 * 4608) / 256, 256, 0, stream>>>(w2, abs2, wq2, 512 * 4608);
    quant_bias_kernel<<<4, 256, 0, stream>>>(b1, b2, abs1, abs2, in_scale, act1_scale, bq1, bq2);

    xform_x_kernel<<<dim3(25, 8, 64), 256, 0, stream>>>(x, xhi, xlo);

    // conv1: 256->512, stride 2, 28->14, hi/lo split input, act1 codes out (NHWC bf16)
    conv_gemm_kernel<256, 2, 28, 14, true, false><<<dim3(8, 196), 256, 0, stream>>>(
        xhi, xlo, wq1, bq1, abs1, act1_scale, act1_scale, act, nullptr);

    // conv2: 512->512, stride 1, 14->14, integer-code input (exact), fp32 NCHW out
    conv_gemm_kernel<512, 1, 14, 14, false, true><<<dim3(8, 196), 256, 0, stream>>>(
        act, nullptr, wq2, bq2, abs2, act1_scale, act2_scale, nullptr, out);
}

// Round 2
// 381.712 us; speedup vs baseline: 1.2843x; 1.2843x over previous
//
#include <hip/hip_runtime.h>

typedef short short8 __attribute__((ext_vector_type(8)));
typedef float f32x4 __attribute__((ext_vector_type(4)));

__device__ __forceinline__ unsigned short f2bf(float f) {
    unsigned u = __float_as_uint(f);
    u += 0x7fffu + ((u >> 16) & 1u);
    return (unsigned short)(u >> 16);
}
__device__ __forceinline__ float bf2f(unsigned short h) {
    return __uint_as_float(((unsigned)h) << 16);
}

// async 16B global->LDS (wave-uniform LDS base + lane*16)
__device__ __forceinline__ void gl_lds16(const unsigned short* g, unsigned short* l) {
    __builtin_amdgcn_global_load_lds(
        (const __attribute__((address_space(1))) void*)g,
        (__attribute__((address_space(3))) void*)l, 16, 0, 0);
}

// ---------------- ws init (2 absmax words) ----------------
__global__ void init_ws_kernel(unsigned* p) {
    if (threadIdx.x < 2) p[threadIdx.x] = 0u;
}

// ---------------- absmax reduction ----------------
__global__ void absmax_kernel(const float* __restrict__ w, int n4, unsigned* __restrict__ out) {
    float m = 0.0f;
    const int stride = gridDim.x * blockDim.x;
    for (int i = blockIdx.x * blockDim.x + threadIdx.x; i < n4; i += stride) {
        float4 v = ((const float4*)w)[i];
        m = fmaxf(m, fmaxf(fmaxf(fabsf(v.x), fabsf(v.y)), fmaxf(fabsf(v.z), fabsf(v.w))));
    }
#pragma unroll
    for (int off = 32; off > 0; off >>= 1)
        m = fmaxf(m, __shfl_down(m, off));
    if ((threadIdx.x & 63) == 0)
        atomicMax(out, __float_as_uint(m));
}

// ---------------- weight fake-quant -> integer codes in bf16, Wt[n][(kh*3+kw)*CIN+cin] ---
template<int CIN>
__global__ void quant_w_kernel(const float* __restrict__ w, const unsigned* __restrict__ absbits,
                               unsigned short* __restrict__ wt, int total) {
    const int idx = blockIdx.x * blockDim.x + threadIdx.x;
    if (idx >= total) return;
    constexpr int K = 9 * CIN;
    const int n = idx / K;
    const int k = idx - n * K;
    const int r = k / CIN;
    const int cin = k - r * CIN;
    const int kh = r / 3;
    const int kw = r - kh * 3;
    const float s = __uint_as_float(*absbits) * (1.0f / 127.0f);
    const float v = w[(((long)n * CIN + cin) * 3 + kh) * 3 + kw];
    float q = rintf(v / s);
    q = fminf(fmaxf(q, -127.0f), 127.0f);   // narrow int8 range
    wt[idx] = f2bf(q);
}

// ---------------- bias Int32 fake-quant ----------------
__global__ void quant_bias_kernel(const float* __restrict__ b1, const float* __restrict__ b2,
                                  const unsigned* __restrict__ a1, const unsigned* __restrict__ a2,
                                  const float* __restrict__ in_scale, const float* __restrict__ act1_scale,
                                  float* __restrict__ bq1, float* __restrict__ bq2) {
    const int i = blockIdx.x * blockDim.x + threadIdx.x;
    if (i < 512) {
        const float s = (*in_scale) * (__uint_as_float(*a1) * (1.0f / 127.0f));
        float q = rintf(b1[i] / s);
        q = fminf(fmaxf(q, -2147483648.0f), 2147483648.0f);
        bq1[i] = q * s;
    } else if (i < 1024) {
        const int j = i - 512;
        const float s = (*act1_scale) * (__uint_as_float(*a2) * (1.0f / 127.0f));
        float q = rintf(b2[j] / s);
        q = fminf(fmaxf(q, -2147483648.0f), 2147483648.0f);
        bq2[j] = q * s;
    }
}

// ---------------- zero halos of padded x (hi/lo) and padded act ----------------
__global__ void zero_halo_kernel(unsigned short* __restrict__ xhi, unsigned short* __restrict__ xlo,
                                 unsigned short* __restrict__ act) {
    constexpr int XCH = 64 * 900 * 32;    // b * (30*30) * (256/8)
    constexpr int ACH = 64 * 256 * 64;    // b * (16*16) * (512/8)
    const int idx = blockIdx.x * blockDim.x + threadIdx.x;
    const uint4 z = {0, 0, 0, 0};
    if (idx < XCH) {
        const int b = idx / (900 * 32);
        const int r = idx - b * (900 * 32);
        const int pos = r >> 5;
        const int ch = r & 31;
        const int h = pos / 30;
        const int w = pos - h * 30;
        if (h == 0 || h == 29 || w == 0 || w == 29) {
            const long off = ((long)(b * 900 + pos)) * 256 + ch * 8;
            *(uint4*)(xhi + off) = z;
            *(uint4*)(xlo + off) = z;
        }
    } else if (idx < XCH + ACH) {
        const int j = idx - XCH;
        const int b = j / (256 * 64);
        const int r = j - b * (256 * 64);
        const int pos = r >> 6;
        const int ch = r & 63;
        const int h = pos >> 4;
        const int w = pos & 15;
        if (h == 0 || h == 15 || w == 0 || w == 15) {
            const long off = ((long)(b * 256 + pos)) * 512 + ch * 8;
            *(uint4*)(act + off) = z;
        }
    }
}

// ---------------- x: fp32 NCHW -> bf16 hi/lo padded NHWC [64][30][30][256] ----------------
__global__ __launch_bounds__(256) void xform_x_kernel(const float* __restrict__ x,
                                                      unsigned short* __restrict__ hi,
                                                      unsigned short* __restrict__ lo) {
    __shared__ float t[32][33];
    const int tx = threadIdx.x & 31;
    const int ty = threadIdx.x >> 5;     // 0..7
    const int b = blockIdx.z;
    const int c0 = blockIdx.y * 32;
    const int hw0 = blockIdx.x * 32;
#pragma unroll
    for (int i = 0; i < 4; ++i) {
        const int c = c0 + ty + i * 8;
        const int hw = hw0 + tx;
        float v = 0.0f;
        if (hw < 784) v = x[((long)b * 256 + c) * 784 + hw];
        t[ty + i * 8][tx] = v;
    }
    __syncthreads();
#pragma unroll
    for (int i = 0; i < 4; ++i) {
        const int hw = hw0 + ty + i * 8;
        const int c = c0 + tx;
        if (hw < 784) {
            const float v = t[tx][ty + i * 8];
            const unsigned short h = f2bf(v);
            const unsigned short l = f2bf(v - bf2f(h));
            const int ph = hw / 28 + 1;
            const int pw = hw - (hw / 28) * 28 + 1;
            const long o = ((long)(b * 900 + ph * 30 + pw)) * 256 + c;
            hi[o] = h;
            lo[o] = l;
        }
    }
}

// ---------------- implicit-GEMM conv, 128x128 tile, global_load_lds staging ----------------
// A: padded NHWC bf16 [B][HP][HP][CIN] (hi/lo codes), Wt: [512][9*CIN] codes in bf16.
// 4 waves; wave (wm,wn) computes 64x64 via 4x4 mfma_f32_16x16x32_bf16.
template<int CIN, int STRIDE, int HP, int HOUT, bool SPLIT, bool FINAL>
__global__ __launch_bounds__(256) void conv_gemm_kernel(
    const unsigned short* __restrict__ Ahi,
    const unsigned short* __restrict__ Alo,
    const unsigned short* __restrict__ Wt,
    const float* __restrict__ bias,
    const unsigned* __restrict__ wabs,
    const float* __restrict__ s_pre,
    const float* __restrict__ s_act,
    unsigned short* __restrict__ act_out,  // !FINAL: padded NHWC bf16 codes [64][16][16][512]
    float* __restrict__ out_final)         // FINAL: NCHW fp32
{
    constexpr int K = 9 * CIN;
    constexpr int HW = HOUT * HOUT;
    constexpr int LOG2CIN = (CIN == 256) ? 8 : 9;
    __shared__ __align__(16) unsigned short As[128 * 32];
    __shared__ __align__(16) unsigned short As2[SPLIT ? 128 * 32 : 16];
    __shared__ __align__(16) unsigned short Bs[128 * 32];

    const int tid = threadIdx.x;
    const int lane = tid & 63;
    const int wv = tid >> 6;
    const int wm = wv & 1;
    const int wn = wv >> 1;
    const int quad = lane >> 4;
    const int l16 = lane & 15;
    const int m0 = blockIdx.y * 128;
    const int n0 = blockIdx.x * 128;

    // staging lane mapping: lane -> (row 0..15, 8-elem chunk)
    const int srow = lane >> 2;
    const int schunk = (lane & 3) * 8;

    long abase[2];
    long bbase[2];
    unsigned short* adst[2];
    unsigned short* a2dst[2];
    unsigned short* bdst[2];
#pragma unroll
    for (int i = 0; i < 2; ++i) {
        const int r = wv * 32 + i * 16 + srow;
        const int m = m0 + r;
        const int b = m / HW;
        const int rem = m - b * HW;
        const int oh = rem / HOUT;
        const int ow = rem - oh * HOUT;
        abase[i] = ((long)((b * HP + oh * STRIDE) * HP + ow * STRIDE)) * CIN + schunk;
        bbase[i] = (long)(n0 + r) * K + schunk;
        adst[i] = &As[(wv * 32 + i * 16) * 32];
        if (SPLIT) a2dst[i] = &As2[(wv * 32 + i * 16) * 32];
        bdst[i] = &Bs[(wv * 32 + i * 16) * 32];
    }

    f32x4 acc[4][4];
#pragma unroll
    for (int mi = 0; mi < 4; ++mi)
#pragma unroll
        for (int ni = 0; ni < 4; ++ni)
            acc[mi][ni] = f32x4{0, 0, 0, 0};

    for (int k0 = 0; k0 < K; k0 += 32) {
        const int r9 = k0 >> LOG2CIN;
        const int c = k0 & (CIN - 1);
        const int kh = r9 / 3;
        const int kw = r9 - kh * 3;
        const long ashift = (long)(kh * HP + kw) * CIN + c;

        __syncthreads();   // previous iter's frag reads done before overwrite
#pragma unroll
        for (int i = 0; i < 2; ++i) {
            gl_lds16(Ahi + abase[i] + ashift, adst[i]);
            if constexpr (SPLIT) gl_lds16(Alo + abase[i] + ashift, a2dst[i]);
            gl_lds16(Wt + bbase[i] + k0, bdst[i]);
        }
        __syncthreads();   // drains vmcnt -> LDS tiles complete

        short8 af[4], bf[4];
#pragma unroll
        for (int mi = 0; mi < 4; ++mi)
            af[mi] = *(const short8*)&As[(wm * 64 + mi * 16 + l16) * 32 + quad * 8];
#pragma unroll
        for (int ni = 0; ni < 4; ++ni)
            bf[ni] = *(const short8*)&Bs[(wn * 64 + ni * 16 + l16) * 32 + quad * 8];
#pragma unroll
        for (int mi = 0; mi < 4; ++mi)
#pragma unroll
            for (int ni = 0; ni < 4; ++ni)
                acc[mi][ni] = __builtin_amdgcn_mfma_f32_16x16x32_bf16(af[mi], bf[ni], acc[mi][ni], 0, 0, 0);
        if constexpr (SPLIT) {
            short8 af2[4];
#pragma unroll
            for (int mi = 0; mi < 4; ++mi)
                af2[mi] = *(const short8*)&As2[(wm * 64 + mi * 16 + l16) * 32 + quad * 8];
#pragma unroll
            for (int mi = 0; mi < 4; ++mi)
#pragma unroll
                for (int ni = 0; ni < 4; ++ni)
                    acc[mi][ni] = __builtin_amdgcn_mfma_f32_16x16x32_bf16(af2[mi], bf[ni], acc[mi][ni], 0, 0, 0);
        }
    }

    // epilogue
    float alpha = __uint_as_float(*wabs) * (1.0f / 127.0f);
    if (FINAL) alpha *= *s_pre;
    const float sact = *s_act;

    float bv[4];
#pragma unroll
    for (int ni = 0; ni < 4; ++ni)
        bv[ni] = bias[n0 + wn * 64 + ni * 16 + l16];

#pragma unroll
    for (int mi = 0; mi < 4; ++mi) {
#pragma unroll
        for (int i = 0; i < 4; ++i) {
            const int m = m0 + wm * 64 + mi * 16 + quad * 4 + i;   // D row = quad*4+i
            const int b = m / HW;
            const int rem = m - b * HW;
            const int oh = rem / HOUT;
            const int ow = rem - oh * HOUT;
#pragma unroll
            for (int ni = 0; ni < 4; ++ni) {
                const int col = n0 + wn * 64 + ni * 16 + l16;       // D col = l16
                const float v = acc[mi][ni][i] * alpha + bv[ni];
                float q = rintf(v / sact);
                q = fminf(fmaxf(q, -128.0f), 127.0f);
                if (FINAL) {
                    out_final[(((long)(b * 512 + col)) * HOUT + oh) * HOUT + ow] = q * sact;
                } else {
                    act_out[((long)(b * 256 + (oh + 1) * 16 + (ow + 1))) * 512 + col] = f2bf(q);
                }
            }
        }
    }
}

// ---------------- launch ----------------
extern "C" void kernel_launch(void* const* d_in, const int* in_sizes, int n_in,
                              void* d_out, int out_size, void* d_ws, size_t ws_size,
                              hipStream_t stream) {
    const float* x  = (const float*)d_in[0];   // 64x256x28x28
    const float* w1 = (const float*)d_in[1];   // 512x256x3x3
    const float* b1 = (const float*)d_in[2];   // 512
    const float* w2 = (const float*)d_in[3];   // 512x512x3x3
    const float* b2 = (const float*)d_in[4];   // 512
    const float* in_scale   = (const float*)d_in[5];
    const float* act1_scale = (const float*)d_in[6];
    const float* act2_scale = (const float*)d_in[7];
    float* out = (float*)d_out;                // 64x512x14x14 NCHW fp32

    char* ws = (char*)d_ws;
    unsigned* abs1 = (unsigned*)(ws + 0);
    unsigned* abs2 = (unsigned*)(ws + 4);
    float* bq1 = (float*)(ws + 64);
    float* bq2 = (float*)(ws + 2112);
    unsigned short* wq1 = (unsigned short*)(ws + 8192);        // 512*2304*2 = 2,359,296
    unsigned short* wq2 = (unsigned short*)(ws + 2367488);     // 512*4608*2 = 4,718,592
    unsigned short* xhi = (unsigned short*)(ws + 7086080);     // 64*900*256*2 = 29,491,200
    unsigned short* xlo = (unsigned short*)(ws + 36577280);    // 29,491,200
    unsigned short* act = (unsigned short*)(ws + 66068480);    // 64*256*512*2 = 16,777,216 -> 82,845,696

    init_ws_kernel<<<1, 64, 0, stream>>>((unsigned*)ws);

    absmax_kernel<<<256, 256, 0, stream>>>(w1, 512 * 256 * 9 / 4, abs1);
    absmax_kernel<<<256, 256, 0, stream>>>(w2, 512 * 512 * 9 / 4, abs2);

    quant_w_kernel<256><<<(512 * 2304) / 256, 256, 0, stream>>>(w1, abs1, wq1, 512 * 2304);
    quant_w_kernel<512><<<(512 * 4608) / 256, 256, 0, stream>>>(w2, abs2, wq2, 512 * 4608);
    quant_bias_kernel<<<4, 256, 0, stream>>>(b1, b2, abs1, abs2, in_scale, act1_scale, bq1, bq2);

    zero_halo_kernel<<<(64 * 900 * 32 + 64 * 256 * 64 + 255) / 256, 256, 0, stream>>>(xhi, xlo, act);
    xform_x_kernel<<<dim3(25, 8, 64), 256, 0, stream>>>(x, xhi, xlo);

    // conv1: 256->512, s2, padded 30x30 in, hi/lo split, padded act codes out
    conv_gemm_kernel<256, 2, 30, 14, true, false><<<dim3(4, 98), 256, 0, stream>>>(
        xhi, xlo, wq1, bq1, abs1, act1_scale, act1_scale, act, nullptr);

    // conv2: 512->512, s1, padded 16x16 in (exact int codes), fp32 NCHW out
    conv_gemm_kernel<512, 1, 16, 14, false, true><<<dim3(4, 98), 256, 0, stream>>>(
        act, nullptr, wq2, bq2, abs2, act1_scale, act2_scale, nullptr, out);
}

// Round 3
// 302.221 us; speedup vs baseline: 1.6221x; 1.2630x over previous
//
#include <hip/hip_runtime.h>

typedef int i32x4 __attribute__((ext_vector_type(4)));

// async 16B global->LDS (wave-uniform LDS base + lane*16; global addr per-lane)
__device__ __forceinline__ void gl_lds16(const signed char* g, signed char* l) {
    __builtin_amdgcn_global_load_lds(
        (const __attribute__((address_space(1))) void*)g,
        (__attribute__((address_space(3))) void*)l, 16, 0, 0);
}

#define XQ_SCALE 2048.0f
#define XQ_DELTA (1.0f / 2048.0f)

// ---------------- ws init (2 absmax words) ----------------
__global__ void init_ws_kernel(unsigned* p) {
    if (threadIdx.x < 2) p[threadIdx.x] = 0u;
}

// ---------------- absmax reduction ----------------
__global__ void absmax_kernel(const float* __restrict__ w, int n4, unsigned* __restrict__ out) {
    float m = 0.0f;
    const int stride = gridDim.x * blockDim.x;
    for (int i = blockIdx.x * blockDim.x + threadIdx.x; i < n4; i += stride) {
        float4 v = ((const float4*)w)[i];
        m = fmaxf(m, fmaxf(fmaxf(fabsf(v.x), fabsf(v.y)), fmaxf(fabsf(v.z), fabsf(v.w))));
    }
#pragma unroll
    for (int off = 32; off > 0; off >>= 1)
        m = fmaxf(m, __shfl_down(m, off));
    if ((threadIdx.x & 63) == 0)
        atomicMax(out, __float_as_uint(m));
}

// ---------------- weight fake-quant -> int8 codes, Wt[n][(kh*3+kw)*CIN+cin] ----------------
template<int CIN>
__global__ void quant_w_kernel(const float* __restrict__ w, const unsigned* __restrict__ absbits,
                               signed char* __restrict__ wt, int total) {
    const int idx = blockIdx.x * blockDim.x + threadIdx.x;
    if (idx >= total) return;
    constexpr int K = 9 * CIN;
    const int n = idx / K;
    const int k = idx - n * K;
    const int r = k / CIN;
    const int cin = k - r * CIN;
    const int kh = r / 3;
    const int kw = r - kh * 3;
    const float s = __uint_as_float(*absbits) * (1.0f / 127.0f);
    const float v = w[(((long)n * CIN + cin) * 3 + kh) * 3 + kw];
    float q = rintf(v / s);
    q = fminf(fmaxf(q, -127.0f), 127.0f);   // narrow int8 range
    wt[idx] = (signed char)(int)q;
}

// ---------------- bias Int32 fake-quant ----------------
__global__ void quant_bias_kernel(const float* __restrict__ b1, const float* __restrict__ b2,
                                  const unsigned* __restrict__ a1, const unsigned* __restrict__ a2,
                                  const float* __restrict__ in_scale, const float* __restrict__ act1_scale,
                                  float* __restrict__ bq1, float* __restrict__ bq2) {
    const int i = blockIdx.x * blockDim.x + threadIdx.x;
    if (i < 512) {
        const float s = (*in_scale) * (__uint_as_float(*a1) * (1.0f / 127.0f));
        float q = rintf(b1[i] / s);
        q = fminf(fmaxf(q, -2147483648.0f), 2147483648.0f);
        bq1[i] = q * s;
    } else if (i < 1024) {
        const int j = i - 512;
        const float s = (*act1_scale) * (__uint_as_float(*a2) * (1.0f / 127.0f));
        float q = rintf(b2[j] / s);
        q = fminf(fmaxf(q, -2147483648.0f), 2147483648.0f);
        bq2[j] = q * s;
    }
}

// ---------------- zero halos of padded x (hi/lo i8) and padded act (i8) ----------------
__global__ void zero_halo_kernel(signed char* __restrict__ xhi, signed char* __restrict__ xlo,
                                 signed char* __restrict__ act) {
    constexpr int XCH = 64 * 900 * 16;    // b * (30*30) * (256/16)
    constexpr int ACH = 64 * 256 * 32;    // b * (16*16) * (512/16)
    const int idx = blockIdx.x * blockDim.x + threadIdx.x;
    const uint4 z = {0, 0, 0, 0};
    if (idx < XCH) {
        const int b = idx / (900 * 16);
        const int r = idx - b * (900 * 16);
        const int pos = r >> 4;
        const int ch = r & 15;
        const int h = pos / 30;
        const int w = pos - h * 30;
        if (h == 0 || h == 29 || w == 0 || w == 29) {
            const long off = ((long)(b * 900 + pos)) * 256 + ch * 16;
            *(uint4*)(xhi + off) = z;
            *(uint4*)(xlo + off) = z;
        }
    } else if (idx < XCH + ACH) {
        const int j = idx - XCH;
        const int b = j / (256 * 32);
        const int r = j - b * (256 * 32);
        const int pos = r >> 5;
        const int ch = r & 31;
        const int h = pos >> 4;
        const int w = pos & 15;
        if (h == 0 || h == 15 || w == 0 || w == 15) {
            const long off = ((long)(b * 256 + pos)) * 512 + ch * 16;
            *(uint4*)(act + off) = z;
        }
    }
}

// ---------------- x: fp32 NCHW -> int15 fixed-point hi/lo i8 planes, padded NHWC [64][30][30][256] --
__global__ __launch_bounds__(256) void xform_x_kernel(const float* __restrict__ x,
                                                      signed char* __restrict__ hi,
                                                      signed char* __restrict__ lo) {
    __shared__ float t[32][33];
    const int tx = threadIdx.x & 31;
    const int ty = threadIdx.x >> 5;     // 0..7
    const int b = blockIdx.z;
    const int c0 = blockIdx.y * 32;
    const int hw0 = blockIdx.x * 32;
#pragma unroll
    for (int i = 0; i < 4; ++i) {
        const int c = c0 + ty + i * 8;
        const int hw = hw0 + tx;
        float v = 0.0f;
        if (hw < 784) v = x[((long)b * 256 + c) * 784 + hw];
        t[ty + i * 8][tx] = v;
    }
    __syncthreads();
#pragma unroll
    for (int i = 0; i < 4; ++i) {
        const int hw = hw0 + ty + i * 8;
        const int c = c0 + tx;
        if (hw < 784) {
            const float v = t[tx][ty + i * 8];
            int q = (int)rintf(v * XQ_SCALE);
            q = max(-16383, min(16383, q));
            const int qh = q >> 7;           // [-128,127]
            const int ql = q & 127;          // [0,127]; q == 128*qh + ql
            const int ph = hw / 28 + 1;
            const int pw = hw - (hw / 28) * 28 + 1;
            const long o = ((long)(b * 900 + ph * 30 + pw)) * 256 + c;
            hi[o] = (signed char)qh;
            lo[o] = (signed char)ql;
        }
    }
}

// ---------------- implicit-GEMM conv, i8 MFMA, 64m x 128n tile ----------------
// A: padded NHWC i8 [B][HP][HP][CIN] (hi/lo fixed-point limbs, or exact act codes).
// Wt: [512][9*CIN] i8 codes. 4 waves (2m x 2n), each 32m x 64n via 2x4 mfma_i32_16x16x64_i8.
template<int CIN, int STRIDE, int HP, int HOUT, int BK, bool SPLIT, bool FINAL>
__global__ __launch_bounds__(256) void conv_gemm_kernel(
    const signed char* __restrict__ Ahi,
    const signed char* __restrict__ Alo,
    const signed char* __restrict__ Wt,
    const float* __restrict__ bias,
    const unsigned* __restrict__ wabs,
    const float* __restrict__ s_pre,
    const float* __restrict__ s_act,
    signed char* __restrict__ act_out,  // !FINAL: padded NHWC i8 codes [64][16][16][512]
    float* __restrict__ out_final)      // FINAL: NCHW fp32
{
    constexpr int K = 9 * CIN;
    constexpr int HW = HOUT * HOUT;
    constexpr int LOG2CIN = (CIN == 256) ? 8 : 9;
    constexpr int RPC = 1024 / BK;    // rows per 1KB gl_lds chunk
    constexpr int LPR = BK / 16;      // lanes per row in a chunk
    constexpr int CA = (BK / 16) / 4; // A chunks per wave
    constexpr int CB = (BK / 8) / 4;  // B chunks per wave
    constexpr int KS = BK / 64;       // k-MFMAs per step

    __shared__ __align__(16) signed char As[64 * BK];
    __shared__ __align__(16) signed char As2[SPLIT ? 64 * BK : 16];
    __shared__ __align__(16) signed char Bs[128 * BK];

    const int tid = threadIdx.x;
    const int lane = tid & 63;
    const int wv = tid >> 6;
    const int wm = wv & 1;
    const int wn = wv >> 1;
    const int quad = lane >> 4;
    const int l16 = lane & 15;
    const int m0 = blockIdx.y * 64;
    const int n0 = blockIdx.x * 128;

    const int lrow = lane / LPR;
    const int koff = (lane % LPR) * 16;

    long abase[CA];
    long bbase[CB];
#pragma unroll
    for (int i = 0; i < CA; ++i) {
        const int r = (wv * CA + i) * RPC + lrow;
        const int m = m0 + r;
        const int b = m / HW;
        const int rem = m - b * HW;
        const int oh = rem / HOUT;
        const int ow = rem - oh * HOUT;
        abase[i] = ((long)((b * HP + oh * STRIDE) * HP + ow * STRIDE)) * CIN + koff;
    }
#pragma unroll
    for (int i = 0; i < CB; ++i) {
        const int r = (wv * CB + i) * RPC + lrow;
        bbase[i] = (long)(n0 + r) * K + koff;
    }

    i32x4 acch[2][4], accl[2][4];
#pragma unroll
    for (int mi = 0; mi < 2; ++mi)
#pragma unroll
        for (int ni = 0; ni < 4; ++ni) {
            acch[mi][ni] = i32x4{0, 0, 0, 0};
            accl[mi][ni] = i32x4{0, 0, 0, 0};
        }

    for (int k0 = 0; k0 < K; k0 += BK) {
        const int r9 = k0 >> LOG2CIN;
        const int c = k0 & (CIN - 1);
        const int kh = r9 / 3;
        const int kw = r9 - kh * 3;
        const long ashift = (long)(kh * HP + kw) * CIN + c;

        __syncthreads();   // previous iter's frag reads done before overwrite
#pragma unroll
        for (int i = 0; i < CA; ++i) {
            gl_lds16(Ahi + abase[i] + ashift, &As[(wv * CA + i) * 1024]);
            if constexpr (SPLIT) gl_lds16(Alo + abase[i] + ashift, &As2[(wv * CA + i) * 1024]);
        }
#pragma unroll
        for (int i = 0; i < CB; ++i)
            gl_lds16(Wt + bbase[i] + k0, &Bs[(wv * CB + i) * 1024]);
        __syncthreads();   // drains vmcnt -> LDS tiles complete

#pragma unroll
        for (int ks = 0; ks < KS; ++ks) {
            i32x4 afh[2], afl[2], bfv[4];
#pragma unroll
            for (int mi = 0; mi < 2; ++mi) {
                afh[mi] = *(const i32x4*)&As[(wm * 32 + mi * 16 + l16) * BK + ks * 64 + quad * 16];
                if constexpr (SPLIT)
                    afl[mi] = *(const i32x4*)&As2[(wm * 32 + mi * 16 + l16) * BK + ks * 64 + quad * 16];
            }
#pragma unroll
            for (int ni = 0; ni < 4; ++ni)
                bfv[ni] = *(const i32x4*)&Bs[(wn * 64 + ni * 16 + l16) * BK + ks * 64 + quad * 16];
#pragma unroll
            for (int mi = 0; mi < 2; ++mi)
#pragma unroll
                for (int ni = 0; ni < 4; ++ni) {
                    acch[mi][ni] = __builtin_amdgcn_mfma_i32_16x16x64_i8(afh[mi], bfv[ni], acch[mi][ni], 0, 0, 0);
                    if constexpr (SPLIT)
                        accl[mi][ni] = __builtin_amdgcn_mfma_i32_16x16x64_i8(afl[mi], bfv[ni], accl[mi][ni], 0, 0, 0);
                }
        }
    }

    // epilogue: dequant, add quantized bias, act fake-quant
    float alpha = __uint_as_float(*wabs) * (1.0f / 127.0f);
    if (FINAL) alpha *= *s_pre;      // conv2: acc * (s_a1 * s_w2)
    if (SPLIT) alpha *= XQ_DELTA;    // conv1: (128*acc_hi + acc_lo) * (delta * s_w1)
    const float sact = *s_act;

    float bv[4];
#pragma unroll
    for (int ni = 0; ni < 4; ++ni)
        bv[ni] = bias[n0 + wn * 64 + ni * 16 + l16];

#pragma unroll
    for (int mi = 0; mi < 2; ++mi) {
#pragma unroll
        for (int i = 0; i < 4; ++i) {
            const int m = m0 + wm * 32 + mi * 16 + quad * 4 + i;   // D row = quad*4+i
            const int b = m / HW;
            const int rem = m - b * HW;
            const int oh = rem / HOUT;
            const int ow = rem - oh * HOUT;
#pragma unroll
            for (int ni = 0; ni < 4; ++ni) {
                const int col = n0 + wn * 64 + ni * 16 + l16;       // D col = l16
                int tot = acch[mi][ni][i];
                if (SPLIT) tot = tot * 128 + accl[mi][ni][i];
                const float v = (float)tot * alpha + bv[ni];
                float q = rintf(v / sact);
                q = fminf(fmaxf(q, -128.0f), 127.0f);
                if (FINAL) {
                    out_final[(((long)(b * 512 + col)) * HOUT + oh) * HOUT + ow] = q * sact;
                } else {
                    act_out[((long)(b * 256 + (oh + 1) * 16 + (ow + 1))) * 512 + col] = (signed char)(int)q;
                }
            }
        }
    }
}

// ---------------- launch ----------------
extern "C" void kernel_launch(void* const* d_in, const int* in_sizes, int n_in,
                              void* d_out, int out_size, void* d_ws, size_t ws_size,
                              hipStream_t stream) {
    const float* x  = (const float*)d_in[0];   // 64x256x28x28
    const float* w1 = (const float*)d_in[1];   // 512x256x3x3
    const float* b1 = (const float*)d_in[2];   // 512
    const float* w2 = (const float*)d_in[3];   // 512x512x3x3
    const float* b2 = (const float*)d_in[4];   // 512
    const float* in_scale   = (const float*)d_in[5];
    const float* act1_scale = (const float*)d_in[6];
    const float* act2_scale = (const float*)d_in[7];
    float* out = (float*)d_out;                // 64x512x14x14 NCHW fp32

    char* ws = (char*)d_ws;
    unsigned* abs1 = (unsigned*)(ws + 0);
    unsigned* abs2 = (unsigned*)(ws + 4);
    float* bq1 = (float*)(ws + 64);
    float* bq2 = (float*)(ws + 2112);
    signed char* wq1 = (signed char*)(ws + 8192);       // 512*2304 = 1,179,648
    signed char* wq2 = (signed char*)(ws + 1187840);    // 512*4608 = 2,359,296
    signed char* xhi = (signed char*)(ws + 3547136);    // 64*900*256 = 14,745,600
    signed char* xlo = (signed char*)(ws + 18292736);   // 14,745,600
    signed char* act = (signed char*)(ws + 33038336);   // 64*256*512 = 8,388,608 -> ends 41,426,944

    init_ws_kernel<<<1, 64, 0, stream>>>((unsigned*)ws);

    absmax_kernel<<<256, 256, 0, stream>>>(w1, 512 * 256 * 9 / 4, abs1);
    absmax_kernel<<<256, 256, 0, stream>>>(w2, 512 * 512 * 9 / 4, abs2);

    quant_w_kernel<256><<<(512 * 2304) / 256, 256, 0, stream>>>(w1, abs1, wq1, 512 * 2304);
    quant_w_kernel<512><<<(512 * 4608) / 256, 256, 0, stream>>>(w2, abs2, wq2, 512 * 4608);
    quant_bias_kernel<<<4, 256, 0, stream>>>(b1, b2, abs1, abs2, in_scale, act1_scale, bq1, bq2);

    zero_halo_kernel<<<(64 * 900 * 16 + 64 * 256 * 32 + 255) / 256, 256, 0, stream>>>(xhi, xlo, act);
    xform_x_kernel<<<dim3(25, 8, 64), 256, 0, stream>>>(x, xhi, xlo);

    // conv1: 256->512, s2, padded 30x30 in, hi/lo i8 limbs, BK=64, padded act codes out
    conv_gemm_kernel<256, 2, 30, 14, 64, true, false><<<dim3(4, 196), 256, 0, stream>>>(
        xhi, xlo, wq1, bq1, abs1, act1_scale, act1_scale, act, nullptr);

    // conv2: 512->512, s1, padded 16x16 in (exact i8 codes), BK=128, fp32 NCHW out
    conv_gemm_kernel<512, 1, 16, 14, 128, false, true><<<dim3(4, 196), 256, 0, stream>>>(
        act, nullptr, wq2, bq2, abs2, act1_scale, act2_scale, nullptr, out);
}

// Round 4
// 261.019 us; speedup vs baseline: 1.8782x; 1.1579x over previous
//
#include <hip/hip_runtime.h>

typedef int i32x4 __attribute__((ext_vector_type(4)));

// async 16B global->LDS (wave-uniform LDS base + lane*16; global addr per-lane)
__device__ __forceinline__ void gl_lds16(const signed char* g, signed char* l) {
    __builtin_amdgcn_global_load_lds(
        (const __attribute__((address_space(1))) void*)g,
        (__attribute__((address_space(3))) void*)l, 16, 0, 0);
}

#define XQ_SCALE 2048.0f
#define XQ_DELTA (1.0f / 2048.0f)

// ---------------- ws init (2 absmax words) ----------------
__global__ void init_ws_kernel(unsigned* p) {
    if (threadIdx.x < 2) p[threadIdx.x] = 0u;
}

// ---------------- absmax of w1 (blocks 0-255) and w2 (blocks 256-511) ----------------
__global__ void absmax2_kernel(const float* __restrict__ w1, const float* __restrict__ w2,
                               unsigned* __restrict__ out) {
    const bool second = blockIdx.x >= 256;
    const float* w = second ? w2 : w1;
    const int n4 = second ? (512 * 512 * 9 / 4) : (512 * 256 * 9 / 4);
    unsigned* o = out + (second ? 1 : 0);
    float m = 0.0f;
    for (int i = (blockIdx.x & 255) * 256 + threadIdx.x; i < n4; i += 65536) {
        float4 v = ((const float4*)w)[i];
        m = fmaxf(m, fmaxf(fmaxf(fabsf(v.x), fabsf(v.y)), fmaxf(fabsf(v.z), fabsf(v.w))));
    }
#pragma unroll
    for (int off = 32; off > 0; off >>= 1)
        m = fmaxf(m, __shfl_down(m, off));
    if ((threadIdx.x & 63) == 0)
        atomicMax(o, __float_as_uint(m));
}

// ---------------- fused prep: quant w1, quant w2, quant bias, zero halos ----------------
__global__ void prep_kernel(const float* __restrict__ w1, const float* __restrict__ w2,
                            const float* __restrict__ b1, const float* __restrict__ b2,
                            const unsigned* __restrict__ absbits,
                            const float* __restrict__ in_scale, const float* __restrict__ act1_scale,
                            signed char* __restrict__ wq1, signed char* __restrict__ wq2,
                            float* __restrict__ bq1, float* __restrict__ bq2,
                            signed char* __restrict__ xhi, signed char* __restrict__ xlo,
                            signed char* __restrict__ act) {
    constexpr int N1 = 512 * 2304;      // w1 codes
    constexpr int N2 = 512 * 4608;      // w2 codes
    constexpr int NB = 1024;            // biases
    constexpr int XH = 64 * 900 * 16;   // x halo 16B chunks
    constexpr int AH = 64 * 256 * 32;   // act halo 16B chunks
    int idx = blockIdx.x * blockDim.x + threadIdx.x;
    const uint4 z = {0, 0, 0, 0};
    if (idx < N1) {
        const int n = idx / 2304;
        const int k = idx - n * 2304;
        const int r = k >> 8;
        const int cin = k & 255;
        const int kh = r / 3;
        const int kw = r - kh * 3;
        const float s = __uint_as_float(absbits[0]) * (1.0f / 127.0f);
        const float v = w1[((n * 256 + cin) * 3 + kh) * 3 + kw];
        float q = rintf(v / s);
        q = fminf(fmaxf(q, -127.0f), 127.0f);
        wq1[idx] = (signed char)(int)q;
    } else if ((idx -= N1) < N2) {
        const int n = idx / 4608;
        const int k = idx - n * 4608;
        const int r = k >> 9;
        const int cin = k & 511;
        const int kh = r / 3;
        const int kw = r - kh * 3;
        const float s = __uint_as_float(absbits[1]) * (1.0f / 127.0f);
        const float v = w2[((n * 512 + cin) * 3 + kh) * 3 + kw];
        float q = rintf(v / s);
        q = fminf(fmaxf(q, -127.0f), 127.0f);
        wq2[idx] = (signed char)(int)q;
    } else if ((idx -= N2) < NB) {
        if (idx < 512) {
            const float s = (*in_scale) * (__uint_as_float(absbits[0]) * (1.0f / 127.0f));
            float q = rintf(b1[idx] / s);
            q = fminf(fmaxf(q, -2147483648.0f), 2147483648.0f);
            bq1[idx] = q * s;
        } else {
            const int j = idx - 512;
            const float s = (*act1_scale) * (__uint_as_float(absbits[1]) * (1.0f / 127.0f));
            float q = rintf(b2[j] / s);
            q = fminf(fmaxf(q, -2147483648.0f), 2147483648.0f);
            bq2[j] = q * s;
        }
    } else if ((idx -= NB) < XH) {
        const int b = idx / (900 * 16);
        const int r = idx - b * (900 * 16);
        const int pos = r >> 4;
        const int ch = r & 15;
        const int h = pos / 30;
        const int w = pos - h * 30;
        if (h == 0 || h == 29 || w == 0 || w == 29) {
            const int off = (b * 900 + pos) * 256 + ch * 16;
            *(uint4*)(xhi + off) = z;
            *(uint4*)(xlo + off) = z;
        }
    } else if ((idx -= XH) < AH) {
        const int b = idx / (256 * 32);
        const int r = idx - b * (256 * 32);
        const int pos = r >> 5;
        const int ch = r & 31;
        const int h = pos >> 4;
        const int w = pos & 15;
        if (h == 0 || h == 15 || w == 0 || w == 15) {
            const int off = (b * 256 + pos) * 512 + ch * 16;
            *(uint4*)(act + off) = z;
        }
    }
}

// ---------------- x: fp32 NCHW -> int15 fixed-point hi/lo i8, padded NHWC [64][30][30][256] ----
__global__ __launch_bounds__(256) void xform_x_kernel(const float* __restrict__ x,
                                                      signed char* __restrict__ hi,
                                                      signed char* __restrict__ lo) {
    __shared__ float t[32][33];
    const int tx = threadIdx.x & 31;
    const int ty = threadIdx.x >> 5;     // 0..7
    const int b = blockIdx.z;
    const int c0 = blockIdx.y * 32;
    const int hw0 = blockIdx.x * 32;
#pragma unroll
    for (int i = 0; i < 4; ++i) {
        const int c = c0 + ty + i * 8;
        const int hw = hw0 + tx;
        float v = 0.0f;
        if (hw < 784) v = x[(b * 256 + c) * 784 + hw];
        t[ty + i * 8][tx] = v;
    }
    __syncthreads();
    if (threadIdx.x < 128) {
        const int hw_l = threadIdx.x >> 2;       // 0..31
        const int cg = (threadIdx.x & 3) * 8;    // 0,8,16,24
        const int hw = hw0 + hw_l;
        if (hw < 784) {
            union { signed char c[8]; uint2 u; } ph, pl;
#pragma unroll
            for (int j = 0; j < 8; ++j) {
                const float v = t[cg + j][hw_l];
                int q = (int)rintf(v * XQ_SCALE);
                q = max(-16383, min(16383, q));
                ph.c[j] = (signed char)(q >> 7);     // [-128,127]
                pl.c[j] = (signed char)(q & 127);    // [0,127]; q == 128*qh + ql
            }
            const int r = hw / 28;
            const int o = (b * 900 + (r + 1) * 30 + (hw - r * 28) + 1) * 256 + c0 + cg;
            *(uint2*)&hi[o] = ph.u;
            *(uint2*)&lo[o] = pl.u;
        }
    }
}

// ---------------- implicit-GEMM conv, i8 MFMA, 64m x 128n block, 2 waves ----------------
// Wave wv covers 64m x 64n (n-half wv). 4x4 frags of mfma_i32_16x16x64_i8; conv1 adds 4
// lo-limb m-frags reusing the same B frags. LDS XOR-swizzled: logical 16B slot s of row r
// stored at physical slot s^(r&7) -> conflict-free ds_read_b128.
template<int CIN, int STRIDE, int HP, int HOUT, bool SPLIT, bool FINAL>
__global__ __launch_bounds__(128, 2) void conv_gemm_kernel(
    const signed char* __restrict__ Ahi,
    const signed char* __restrict__ Alo,
    const signed char* __restrict__ Wt,
    const float* __restrict__ bias,
    const unsigned* __restrict__ wabs,
    const float* __restrict__ s_pre,
    const float* __restrict__ s_act,
    signed char* __restrict__ act_out,  // !FINAL: padded NHWC i8 codes [64][16][16][512]
    float* __restrict__ out_final)      // FINAL: NCHW fp32
{
    constexpr int K = 9 * CIN;
    constexpr int HW = HOUT * HOUT;
    constexpr int LOG2CIN = (CIN == 256) ? 8 : 9;
    constexpr int NACC = SPLIT ? 8 : 4;

    __shared__ __align__(16) signed char As[64 * 128];                 // 8KB
    __shared__ __align__(16) signed char As2[SPLIT ? 64 * 128 : 16];   // 8KB (conv1)
    __shared__ __align__(16) signed char Bs[128 * 128];                // 16KB

    const int tid = threadIdx.x;
    const int lane = tid & 63;
    const int wv = tid >> 6;            // 0..1; wave n-half
    const int quad = lane >> 4;
    const int l16 = lane & 15;
    const int m0 = blockIdx.y * 64;
    const int n0 = blockIdx.x * 128;

    // staging: chunk = 1KB = 8 rows x 128B; lane -> (row lane>>3, physical slot lane&7)
    const int lrow = lane >> 3;
    const int koff = ((lane & 7) ^ lrow) * 16;   // swizzled logical k-offset

    int aoff[8];
    int boff[16];
    if (wv == 0) {
#pragma unroll
        for (int c = 0; c < 8; ++c) {
            const int r = c * 8 + lrow;
            const int m = m0 + r;
            const int b = m / HW;
            const int rem = m - b * HW;
            const int oh = rem / HOUT;
            const int ow = rem - oh * HOUT;
            aoff[c] = ((b * HP + oh * STRIDE) * HP + ow * STRIDE) * CIN + koff;
        }
    } else {
#pragma unroll
        for (int c = 0; c < 16; ++c)
            boff[c] = (n0 + c * 8 + lrow) * K + koff;
    }

    i32x4 acc[NACC][4];
#pragma unroll
    for (int mi = 0; mi < NACC; ++mi)
#pragma unroll
        for (int ni = 0; ni < 4; ++ni)
            acc[mi][ni] = i32x4{0, 0, 0, 0};

    for (int k0 = 0; k0 < K; k0 += 128) {
        const int r9 = k0 >> LOG2CIN;
        const int c0k = k0 & (CIN - 1);
        const int kh = r9 / 3;
        const int kw = r9 - kh * 3;
        const int ashift = (kh * HP + kw) * CIN + c0k;

        __syncthreads();   // previous iter's frag reads done before overwrite
        if (wv == 0) {
#pragma unroll
            for (int c = 0; c < 8; ++c) {
                gl_lds16(Ahi + aoff[c] + ashift, &As[c * 1024]);
                if constexpr (SPLIT) gl_lds16(Alo + aoff[c] + ashift, &As2[c * 1024]);
            }
        } else {
#pragma unroll
            for (int c = 0; c < 16; ++c)
                gl_lds16(Wt + boff[c] + k0, &Bs[c * 1024]);
        }
        __syncthreads();   // vmcnt drained -> LDS tiles complete

#pragma unroll
        for (int ks = 0; ks < 2; ++ks) {
            i32x4 af[NACC];
            i32x4 bfr[4];
#pragma unroll
            for (int mi = 0; mi < 4; ++mi) {
                const int row = mi * 16 + l16;
                const int sl = ((ks * 4 + quad) ^ (row & 7)) * 16;
                af[mi] = *(const i32x4*)&As[row * 128 + sl];
                if constexpr (SPLIT)
                    af[mi + 4] = *(const i32x4*)&As2[row * 128 + sl];
            }
#pragma unroll
            for (int ni = 0; ni < 4; ++ni) {
                const int row = wv * 64 + ni * 16 + l16;
                const int sl = ((ks * 4 + quad) ^ (row & 7)) * 16;
                bfr[ni] = *(const i32x4*)&Bs[row * 128 + sl];
            }
#pragma unroll
            for (int mi = 0; mi < 4; ++mi)
#pragma unroll
                for (int ni = 0; ni < 4; ++ni) {
                    acc[mi][ni] = __builtin_amdgcn_mfma_i32_16x16x64_i8(af[mi], bfr[ni], acc[mi][ni], 0, 0, 0);
                    if constexpr (SPLIT)
                        acc[mi + 4][ni] = __builtin_amdgcn_mfma_i32_16x16x64_i8(af[mi + 4], bfr[ni], acc[mi + 4][ni], 0, 0, 0);
                }
        }
    }

    // epilogue: dequant, add quantized bias, act fake-quant
    float alpha = __uint_as_float(*wabs) * (1.0f / 127.0f);
    if (FINAL) alpha *= *s_pre;      // conv2: acc * (s_a1 * s_w2)
    if (SPLIT) alpha *= XQ_DELTA;    // conv1: (128*acc_hi + acc_lo) * (delta * s_w1)
    const float sact = *s_act;

    float bv[4];
#pragma unroll
    for (int ni = 0; ni < 4; ++ni)
        bv[ni] = bias[n0 + wv * 64 + ni * 16 + l16];

#pragma unroll
    for (int mi = 0; mi < 4; ++mi) {
#pragma unroll
        for (int i = 0; i < 4; ++i) {
            const int m = m0 + mi * 16 + quad * 4 + i;   // D row = quad*4+i
            const int b = m / HW;
            const int rem = m - b * HW;
            const int oh = rem / HOUT;
            const int ow = rem - oh * HOUT;
#pragma unroll
            for (int ni = 0; ni < 4; ++ni) {
                const int col = n0 + wv * 64 + ni * 16 + l16;   // D col = l16
                int tot = acc[mi][ni][i];
                if constexpr (SPLIT) tot = tot * 128 + acc[mi + 4][ni][i];
                const float v = (float)tot * alpha + bv[ni];
                float q = rintf(v / sact);
                q = fminf(fmaxf(q, -128.0f), 127.0f);
                if (FINAL) {
                    out_final[(b * 512 + col) * HW + oh * HOUT + ow] = q * sact;
                } else {
                    act_out[(b * 256 + (oh + 1) * 16 + (ow + 1)) * 512 + col] = (signed char)(int)q;
                }
            }
        }
    }
}

// ---------------- launch ----------------
extern "C" void kernel_launch(void* const* d_in, const int* in_sizes, int n_in,
                              void* d_out, int out_size, void* d_ws, size_t ws_size,
                              hipStream_t stream) {
    const float* x  = (const float*)d_in[0];   // 64x256x28x28
    const float* w1 = (const float*)d_in[1];   // 512x256x3x3
    const float* b1 = (const float*)d_in[2];   // 512
    const float* w2 = (const float*)d_in[3];   // 512x512x3x3
    const float* b2 = (const float*)d_in[4];   // 512
    const float* in_scale   = (const float*)d_in[5];
    const float* act1_scale = (const float*)d_in[6];
    const float* act2_scale = (const float*)d_in[7];
    float* out = (float*)d_out;                // 64x512x14x14 NCHW fp32

    char* ws = (char*)d_ws;
    unsigned* absbits = (unsigned*)(ws + 0);
    float* bq1 = (float*)(ws + 64);
    float* bq2 = (float*)(ws + 2112);
    signed char* wq1 = (signed char*)(ws + 8192);       // 512*2304 = 1,179,648
    signed char* wq2 = (signed char*)(ws + 1187840);    // 512*4608 = 2,359,296
    signed char* xhi = (signed char*)(ws + 3547136);    // 64*900*256 = 14,745,600
    signed char* xlo = (signed char*)(ws + 18292736);   // 14,745,600
    signed char* act = (signed char*)(ws + 33038336);   // 64*256*512 = 8,388,608 -> ends 41,426,944

    init_ws_kernel<<<1, 64, 0, stream>>>(absbits);
    absmax2_kernel<<<512, 256, 0, stream>>>(w1, w2, absbits);

    // fused: quant w1 + quant w2 + quant bias + zero halos
    constexpr int PREP_TOTAL = 512 * 2304 + 512 * 4608 + 1024 + 64 * 900 * 16 + 64 * 256 * 32;
    prep_kernel<<<(PREP_TOTAL + 255) / 256, 256, 0, stream>>>(
        w1, w2, b1, b2, absbits, in_scale, act1_scale, wq1, wq2, bq1, bq2, xhi, xlo, act);

    xform_x_kernel<<<dim3(25, 8, 64), 256, 0, stream>>>(x, xhi, xlo);

    // conv1: 256->512, s2, padded 30x30 in, hi/lo i8 limbs, padded act codes out
    conv_gemm_kernel<256, 2, 30, 14, true, false><<<dim3(4, 196), 128, 0, stream>>>(
        xhi, xlo, wq1, bq1, absbits, act1_scale, act1_scale, act, nullptr);

    // conv2: 512->512, s1, padded 16x16 in (exact i8 codes), fp32 NCHW out
    conv_gemm_kernel<512, 1, 16, 14, false, true><<<dim3(4, 196), 128, 0, stream>>>(
        act, nullptr, wq2, bq2, absbits + 1, act1_scale, act2_scale, nullptr, out);
}